// Round 3
// baseline (500.500 us; speedup 1.0000x reference)
//
#include <hip/hip_runtime.h>
#include <stdint.h>

// Problem sizes.
static constexpr int Bn = 4096;
static constexpr int Dn = 5000;
static constexpr int Hn = 2000;
static constexpr int Ln = 50;
static constexpr int XW = 80;          // u64 words per D-length row (79 used, pad 80 = 5120 cols)
static constexpr int ZW = 32;          // u64 words per H-length row (2048 bits)
static constexpr int Hpad = 2048;      // 32 j-chunks of 64
static constexpr int NDC = 79;         // d-chunks of 64
static constexpr int Dpad = NDC * 64;  // 5056

__device__ __forceinline__ int popc_acc(uint64_t v, int acc) {
  // v_bcnt_u32_b32 has fused "+S1" accumulate.
  acc = __builtin_popcount((uint32_t)v) + acc;
  acc = __builtin_popcount((uint32_t)(v >> 32)) + acc;
  return acc;
}

// Pack x rows into TRANSPOSED bit matrix xbT[w][b]; 4 words per wave, coalesced reads.
__global__ void k_pack_x(const float* __restrict__ x, uint64_t* __restrict__ xbT) {
  int g = (int)((blockIdx.x * blockDim.x + threadIdx.x) >> 6);
  int lane = (int)(threadIdx.x & 63);
  constexpr int nq = XW >> 2;  // 20
  int row = g / nq;
  int q = g - row * nq;
  if (row >= Bn) return;
  int w0 = q << 2;
  unsigned long long m[4];
#pragma unroll
  for (int e = 0; e < 4; ++e) {
    int col = ((w0 + e) << 6) + lane;
    float v = (col < Dn) ? x[(size_t)row * Dn + col] : 0.0f;
    m[e] = __ballot(v >= 0.5f);
  }
  if (lane < 4) {
    unsigned long long mv = m[0];
    mv = (lane == 1) ? m[1] : mv;
    mv = (lane == 2) ? m[2] : mv;
    mv = (lane == 3) ? m[3] : mv;
    xbT[(size_t)(w0 + lane) * Bn + row] = mv;
  }
}

// One coalesced read of W produces BOTH row bitsets (wbits[j][w], ballots over d-lanes)
// and column bitsets (wtbits[d][jw], per-thread bit accumulation over 64 rows).
// Tile: 64 j-rows x 256 d-cols per block. Padded rows/cols come out zero.
__global__ __launch_bounds__(256) void k_pack_w(const float* __restrict__ W,
                                                uint64_t* __restrict__ wbits,
                                                uint64_t* __restrict__ wtbits) {
  int d = blockIdx.x * 256 + (int)threadIdx.x;  // 0..5119
  int j0 = (int)blockIdx.y * 64;                // 0..1984
  int lane = (int)(threadIdx.x & 63);
  int wv = (int)(threadIdx.x >> 6);             // wave in block: d-word sub-index
  uint64_t colbits = 0;
  for (int r = 0; r < 64; ++r) {
    int j = j0 + r;
    float v = (j < Hn && d < Dn) ? W[(size_t)j * Dn + d] : 0.0f;
    bool bit = v >= 0.5f;
    colbits |= ((uint64_t)(bit ? 1u : 0u)) << r;
    unsigned long long m = __ballot(bit);
    if (lane == 0) wbits[(size_t)j * XW + (blockIdx.x * 4 + wv)] = m;
  }
  if (d < Dpad) wtbits[(size_t)d * ZW + blockIdx.y] = colbits;
}

// fwT[j][l] = sigmoid(2 * cw[l][j]), padded to 64 cols (pad = 0).
__global__ void k_pack_fwT(const float* __restrict__ cw, float* __restrict__ fwT) {
  int idx = blockIdx.x * blockDim.x + threadIdx.x;
  if (idx >= Hn * 64) return;
  int j = idx >> 6, l = idx & 63;
  float v = 0.0f;
  if (l < Ln) {
    float t = 2.0f * cw[(size_t)l * Hn + j];
    v = 1.0f / (1.0f + expf(-t));
  }
  fwT[idx] = v;
}

__global__ void k_zero(float* __restrict__ p, int n) {
  int i = blockIdx.x * blockDim.x + threadIdx.x;
  if (i < n) p[i] = 0.0f;
}

// Encoder: lane owns batch row b; x row bits held in 160 VGPRs; weight rows stream
// through SGPRs (s_load). Wave covers 64 consecutive j, so z bits pack per-lane.
// Writes z floats (16B stores, full-line) and z row-bits for the decoder.
__global__ __launch_bounds__(256, 2) void k_enc(const uint64_t* __restrict__ xbT,
                                                const uint64_t* __restrict__ wbits,
                                                const float* __restrict__ b_enc,
                                                const float* __restrict__ act0_bias,
                                                float* __restrict__ z_out,
                                                uint64_t* __restrict__ zbits) {
  int wv = __builtin_amdgcn_readfirstlane((int)threadIdx.x >> 6);
  int gw = (int)blockIdx.x * 4 + wv;  // 0..2047
  int lane = (int)threadIdx.x & 63;
  int jchunk = gw & 31;   // 32 chunks x 64 j
  int bgroup = gw >> 5;   // 64 groups x 64 b
  int b = (bgroup << 6) + lane;
  int jbase = jchunk << 6;

  uint64_t xr[XW];
#pragma unroll
  for (int w = 0; w < XW; ++w) xr[w] = xbT[(size_t)w * Bn + b];

  uint64_t zword = 0;
#pragma unroll 1
  for (int jj = 0; jj < 64; jj += 2) {
    int j0 = jbase + jj;  // wave-uniform
    const uint64_t* w0 = wbits + (size_t)j0 * XW;
    int a0 = 0, a1 = 0;
#pragma unroll
    for (int w = 0; w < XW; ++w) {
      a0 = popc_acc(xr[w] & w0[w], a0);
      a1 = popc_acc(xr[w] & w0[XW + w], a1);
    }
    float be0 = (j0 < Hn) ? b_enc[j0] : 0.0f;
    float be1 = (j0 + 1 < Hn) ? b_enc[j0 + 1] : 0.0f;
    float ab0 = (j0 < Hn) ? act0_bias[j0] : 0.0f;
    float ab1 = (j0 + 1 < Hn) ? act0_bias[j0 + 1] : 0.0f;
    float h0 = ((float)a0 + be0) + ab0;  // exact: small int + fp32, reference order
    float h1 = ((float)a1 + be1) + ab1;
    zword |= ((uint64_t)(h0 >= 1.0f ? 1u : 0u)) << jj;
    zword |= ((uint64_t)(h1 >= 1.0f ? 1u : 0u)) << (jj + 1);
  }
  zbits[(size_t)b * ZW + jchunk] = zword;
  float* zp = z_out + (size_t)b * Hn + jbase;
#pragma unroll
  for (int g = 0; g < 16; ++g) {
    if (jbase + g * 4 < Hn) {  // uniform
      float4 f;
      f.x = (float)((zword >> (4 * g + 0)) & 1ull);
      f.y = (float)((zword >> (4 * g + 1)) & 1ull);
      f.z = (float)((zword >> (4 * g + 2)) & 1ull);
      f.w = (float)((zword >> (4 * g + 3)) & 1ull);
      *(float4*)(zp + 4 * g) = f;
    }
  }
}

// Decoder: lane owns batch row b; z row bits in 64 VGPRs; weight columns stream
// through SGPRs. Wave covers 64 consecutive d; writes out floats directly.
__global__ __launch_bounds__(256, 4) void k_dec(const uint64_t* __restrict__ zbits,
                                                const uint64_t* __restrict__ wtbits,
                                                const float* __restrict__ act3_bias,
                                                float* __restrict__ out) {
  int wv = __builtin_amdgcn_readfirstlane((int)threadIdx.x >> 6);
  int gw = (int)blockIdx.x * 4 + wv;  // 0..5055
  int lane = (int)threadIdx.x & 63;
  int dchunk = gw % NDC;
  int bgroup = gw / NDC;
  int b = (bgroup << 6) + lane;
  int dbase = dchunk << 6;

  uint64_t zr[ZW];
#pragma unroll
  for (int w = 0; w < ZW; ++w) zr[w] = zbits[(size_t)b * ZW + w];

  uint64_t oword = 0;
#pragma unroll 1
  for (int dd = 0; dd < 64; dd += 2) {
    int d0 = dbase + dd;  // wave-uniform
    const uint64_t* t0 = wtbits + (size_t)d0 * ZW;
    int a0 = 0, a1 = 0;
#pragma unroll
    for (int w = 0; w < ZW; ++w) {
      a0 = popc_acc(zr[w] & t0[w], a0);
      a1 = popc_acc(zr[w] & t0[ZW + w], a1);
    }
    float ab0 = (d0 < Dn) ? act3_bias[d0] : 0.0f;
    float ab1 = (d0 + 1 < Dn) ? act3_bias[d0 + 1] : 0.0f;
    oword |= ((uint64_t)((((float)a0 + ab0) >= 1.0f) ? 1u : 0u)) << dd;
    oword |= ((uint64_t)((((float)a1 + ab1) >= 1.0f) ? 1u : 0u)) << (dd + 1);
  }
  float* op = out + (size_t)b * Dn + dbase;
#pragma unroll
  for (int g = 0; g < 16; ++g) {
    if (dbase + g * 4 < Dn) {  // uniform; chunk 78 stores exactly 2 float4
      float4 f;
      f.x = (float)((oword >> (4 * g + 0)) & 1ull);
      f.y = (float)((oword >> (4 * g + 1)) & 1ull);
      f.z = (float)((oword >> (4 * g + 2)) & 1ull);
      f.w = (float)((oword >> (4 * g + 3)) & 1ull);
      *(float4*)(op + 4 * g) = f;
    }
  }
}

// classification[b][l] = sum_j z[b][j] * fwT[j][l]; partials via atomicAdd.
__global__ __launch_bounds__(256) void k_cls(const float* __restrict__ z,
                                             const float* __restrict__ fwT,
                                             float* __restrict__ cls) {
  constexpr int TB = 4, JSPLIT = 16, CH = Hn / JSPLIT;  // 125
  int gw = (int)((blockIdx.x * blockDim.x + threadIdx.x) >> 6);
  int lane = (int)(threadIdx.x & 63);
  int bq = __builtin_amdgcn_readfirstlane(gw / JSPLIT);
  int jc = __builtin_amdgcn_readfirstlane(gw - bq * JSPLIT);
  int b0 = bq * TB;
  float acc[TB];
#pragma unroll
  for (int i = 0; i < TB; ++i) acc[i] = 0.0f;
  const float* zp = z + (size_t)b0 * Hn + (size_t)jc * CH;  // uniform -> scalar loads
  const float* fp = fwT + (size_t)jc * CH * 64 + lane;      // coalesced
#pragma unroll 5
  for (int t = 0; t < CH; ++t) {
    float fwv = fp[(size_t)t * 64];
#pragma unroll
    for (int i = 0; i < TB; ++i) acc[i] += zp[(size_t)i * Hn + t] * fwv;
  }
  if (lane < Ln) {
#pragma unroll
    for (int i = 0; i < TB; ++i)
      atomicAdd(&cls[(size_t)(b0 + i) * Ln + lane], acc[i]);
  }
}

extern "C" void kernel_launch(void* const* d_in, const int* in_sizes, int n_in,
                              void* d_out, int out_size, void* d_ws, size_t ws_size,
                              hipStream_t stream) {
  const float* x     = (const float*)d_in[0];  // [B][D]
  const float* W     = (const float*)d_in[1];  // [H][D]
  const float* b_enc = (const float*)d_in[2];  // [H]
  const float* act0b = (const float*)d_in[3];  // [H]
  const float* act3b = (const float*)d_in[4];  // [D]
  const float* cw    = (const float*)d_in[5];  // [L][H]

  float* out0 = (float*)d_out;              // output        [B][D]
  float* cls  = out0 + (size_t)Bn * Dn;     // classification[B][L]
  float* zout = cls + (size_t)Bn * Ln;      // z             [B][H]

  // Workspace (~6.8 MB).
  char* ws = (char*)d_ws;
  uint64_t* xbT    = (uint64_t*)ws; ws += (size_t)XW * Bn * 8;    // 2.62 MB [XW][Bn]
  uint64_t* wbits  = (uint64_t*)ws; ws += (size_t)Hpad * XW * 8;  // 1.31 MB [Hpad][XW]
  uint64_t* wtbits = (uint64_t*)ws; ws += (size_t)Dpad * ZW * 8;  // 1.29 MB [Dpad][ZW]
  uint64_t* zbits  = (uint64_t*)ws; ws += (size_t)Bn * ZW * 8;    // 1.05 MB [Bn][ZW]
  float*    fwT    = (float*)ws;    ws += (size_t)Hn * 64 * 4;    // 0.51 MB

  {  // x -> xbT (word-major transpose)
    long long waves = (long long)Bn * (XW / 4);
    k_pack_x<<<(int)((waves * 64 + 255) / 256), 256, 0, stream>>>(x, xbT);
  }
  {  // W -> wbits + wtbits in one coalesced pass
    dim3 g((Dpad + 255 + 63) / 256 + 0, Hpad / 64);  // x: ceil(5120/256)=20, y: 32
    dim3 gw2(20, 32);
    k_pack_w<<<gw2, 256, 0, stream>>>(W, wbits, wtbits);
  }
  k_pack_fwT<<<(Hn * 64 + 255) / 256, 256, 0, stream>>>(cw, fwT);
  k_zero<<<(Bn * Ln + 255) / 256, 256, 0, stream>>>(cls, Bn * Ln);

  // enc: 2048 waves = 512 blocks
  k_enc<<<512, 256, 0, stream>>>(xbT, wbits, b_enc, act0b, zout, zbits);

  {  // cls: (Bn/4)*16 waves
    long long waves = (long long)(Bn / 4) * 16;
    k_cls<<<(int)((waves * 64 + 255) / 256), 256, 0, stream>>>(zout, fwT, cls);
  }

  // dec: 64 bgroups * 79 dchunks = 5056 waves = 1264 blocks
  k_dec<<<1264, 256, 0, stream>>>(zbits, wtbits, act3b, out0);
}